// Round 3
// baseline (1109.599 us; speedup 1.0000x reference)
//
#include <hip/hip_runtime.h>
#include <math.h>
#include <float.h>

#define NROWS 16384
#define KCODES 8192
#define DIM 256
#define KSPLIT 8
#define KCHUNK 1024
#define BM 128
#define BN 128
#define BKD 16
#define ZPAD 136
#define EPAD 192

// ws layout (4B units)
#define WS_CIDX 0                        // 16384*8 int4 = 524288 ints (2 MB)
#define WS_ZZ   (NROWS * KSPLIT * 4)     // 16384 floats
#define WS_EE   (WS_ZZ + NROWS)          // 8192 floats
#define WS_LOSS (WS_EE + KCODES)         // 1 float

// ---- exact numpy scalar-pairwise sum of squares over 256 contiguous f32 ----
// (split 128+128; each: 8 accumulators r[j] += x[i+j]; tree-combine)
__device__ __forceinline__ float np_sumsq256(const float* __restrict__ p) {
#pragma clang fp contract(off)
  float s0 = 0.f, s1 = 0.f;
  for (int h = 0; h < 2; ++h) {
    const float* x = p + h * 128;
    float r0, r1, r2, r3, r4, r5, r6, r7;
    {
      float4 a = *reinterpret_cast<const float4*>(x);
      float4 b = *reinterpret_cast<const float4*>(x + 4);
      r0 = a.x * a.x; r1 = a.y * a.y; r2 = a.z * a.z; r3 = a.w * a.w;
      r4 = b.x * b.x; r5 = b.y * b.y; r6 = b.z * b.z; r7 = b.w * b.w;
    }
    for (int g = 1; g < 16; ++g) {
      float4 a = *reinterpret_cast<const float4*>(x + g * 8);
      float4 b = *reinterpret_cast<const float4*>(x + g * 8 + 4);
      float p0 = a.x * a.x, p1 = a.y * a.y, p2 = a.z * a.z, p3 = a.w * a.w;
      float p4 = b.x * b.x, p5 = b.y * b.y, p6 = b.z * b.z, p7 = b.w * b.w;
      r0 += p0; r1 += p1; r2 += p2; r3 += p3;
      r4 += p4; r5 += p5; r6 += p6; r7 += p7;
    }
    float t = ((r0 + r1) + (r2 + r3)) + ((r4 + r5) + (r6 + r7));
    if (h == 0) s0 = t; else s1 = t;
  }
  return s0 + s1;
}

__global__ __launch_bounds__(256) void vq_prep_zz(const float* __restrict__ z,
                                                  float* __restrict__ zz,
                                                  float* __restrict__ lossAcc) {
  const int row = blockIdx.x * 256 + threadIdx.x;
  if (row == 0) *lossAcc = 0.0f;
  zz[row] = np_sumsq256(z + row * DIM);
}

__global__ __launch_bounds__(256) void vq_prep_ee(const float* __restrict__ emb,
                                                  float* __restrict__ ee) {
  const int c = blockIdx.x * 256 + threadIdx.x;
  ee[c] = np_sumsq256(emb + c * DIM);
}

// ---- keyed compare-exchange helpers (constant indices only -> registers) ----
__device__ __forceinline__ void ce(float& va, int& ia, float& vb, int& ib) {
  if (vb < va) { float tv = va; va = vb; vb = tv; int ti = ia; ia = ib; ib = ti; }
}
__device__ __forceinline__ void mn(float& va, int& ia, float vb, int ib) {
  if (vb < va) { va = vb; ia = ib; }
}
// merge two ascending 4-lists -> ascending smallest-4 (bitonic lower half)
__device__ __forceinline__ void merge4(float* m, int* j, const float* o, const int* p) {
  float t0 = m[0], t1 = m[1], t2 = m[2], t3 = m[3];
  int u0 = j[0], u1 = j[1], u2 = j[2], u3 = j[3];
  mn(t0, u0, o[3], p[3]); mn(t1, u1, o[2], p[2]);
  mn(t2, u2, o[1], p[1]); mn(t3, u3, o[0], p[0]);
  ce(t0, u0, t2, u2); ce(t1, u1, t3, u3);
  ce(t0, u0, t1, u1); ce(t2, u2, t3, u3);
  m[0] = t0; m[1] = t1; m[2] = t2; m[3] = t3;
  j[0] = u0; j[1] = u1; j[2] = u2; j[3] = u3;
}

// ---------------- stage A: fp32 tiled GEMM + per-row top-4 per K-range ----------------
__global__ __launch_bounds__(256) void vq_stageA(const float* __restrict__ z,
                                                 const float* __restrict__ emb,
                                                 int4* __restrict__ candIdx) {
  __shared__ float zts[BKD * ZPAD];
  __shared__ float ets[BKD * EPAD];
  const int tid = threadIdx.x;
  const int ks = blockIdx.x;
  const int row0 = blockIdx.y * BM;
  const int k0 = ks * KCHUNK;
  const int tc = tid & 15;
  const int tr = tid >> 4;
  const int lr = tid >> 1;
  const int ldh = (tid & 1) * 8;
  const int lcid = lr + ((lr >> 3) << 2);

  float mrun[8][4];
  int jrun[8][4];
  #pragma unroll
  for (int i = 0; i < 8; ++i)
    #pragma unroll
    for (int q = 0; q < 4; ++q) { mrun[i][q] = FLT_MAX; jrun[i][q] = 0x7ffffff; }

  for (int cc = 0; cc < KCHUNK / BN; ++cc) {
    const int c0 = k0 + cc * BN;
    float acc[8][8];
    #pragma unroll
    for (int i = 0; i < 8; ++i)
      #pragma unroll
      for (int j = 0; j < 8; ++j) acc[i][j] = 0.0f;

    for (int dc = 0; dc < DIM / BKD; ++dc) {
      const int d0 = dc * BKD;
      const float4 za = *reinterpret_cast<const float4*>(z + (row0 + lr) * DIM + d0 + ldh);
      const float4 zb = *reinterpret_cast<const float4*>(z + (row0 + lr) * DIM + d0 + ldh + 4);
      const float4 ea = *reinterpret_cast<const float4*>(emb + (c0 + lr) * DIM + d0 + ldh);
      const float4 eb = *reinterpret_cast<const float4*>(emb + (c0 + lr) * DIM + d0 + ldh + 4);
      __syncthreads();
      zts[(ldh + 0) * ZPAD + lr] = za.x;
      zts[(ldh + 1) * ZPAD + lr] = za.y;
      zts[(ldh + 2) * ZPAD + lr] = za.z;
      zts[(ldh + 3) * ZPAD + lr] = za.w;
      zts[(ldh + 4) * ZPAD + lr] = zb.x;
      zts[(ldh + 5) * ZPAD + lr] = zb.y;
      zts[(ldh + 6) * ZPAD + lr] = zb.z;
      zts[(ldh + 7) * ZPAD + lr] = zb.w;
      ets[(ldh + 0) * EPAD + lcid] = ea.x;
      ets[(ldh + 1) * EPAD + lcid] = ea.y;
      ets[(ldh + 2) * EPAD + lcid] = ea.z;
      ets[(ldh + 3) * EPAD + lcid] = ea.w;
      ets[(ldh + 4) * EPAD + lcid] = eb.x;
      ets[(ldh + 5) * EPAD + lcid] = eb.y;
      ets[(ldh + 6) * EPAD + lcid] = eb.z;
      ets[(ldh + 7) * EPAD + lcid] = eb.w;
      __syncthreads();
      for (int dd = 0; dd < BKD; ++dd) {
        const float4 x0 = *reinterpret_cast<const float4*>(&zts[dd * ZPAD + tr * 8]);
        const float4 x1 = *reinterpret_cast<const float4*>(&zts[dd * ZPAD + tr * 8 + 4]);
        const float4 y0 = *reinterpret_cast<const float4*>(&ets[dd * EPAD + tc * 12]);
        const float4 y1 = *reinterpret_cast<const float4*>(&ets[dd * EPAD + tc * 12 + 4]);
        const float zr[8] = {x0.x, x0.y, x0.z, x0.w, x1.x, x1.y, x1.z, x1.w};
        const float er[8] = {y0.x, y0.y, y0.z, y0.w, y1.x, y1.y, y1.z, y1.w};
        #pragma unroll
        for (int i = 0; i < 8; ++i)
          #pragma unroll
          for (int j = 0; j < 8; ++j)
            acc[i][j] = fmaf(zr[i], er[j], acc[i][j]);
      }
    }

    // approx score = -acc (ranking identical to np's effective -2*mm; ee irrelevant at 2e-7 scale)
    #pragma unroll
    for (int i = 0; i < 8; ++i) {
      const int base = c0 + tc * 8;
      float a0 = -acc[i][0], a1 = -acc[i][1], a2 = -acc[i][2], a3 = -acc[i][3];
      float a4 = -acc[i][4], a5 = -acc[i][5], a6 = -acc[i][6], a7 = -acc[i][7];
      int x0 = base, x1 = base + 1, x2 = base + 2, x3 = base + 3;
      int x4 = base + 4, x5 = base + 5, x6 = base + 6, x7 = base + 7;
      // sort4 halves (ascending)
      ce(a0, x0, a1, x1); ce(a2, x2, a3, x3); ce(a0, x0, a2, x2); ce(a1, x1, a3, x3); ce(a1, x1, a2, x2);
      ce(a4, x4, a5, x5); ce(a6, x6, a7, x7); ce(a4, x4, a6, x6); ce(a5, x5, a7, x7); ce(a5, x5, a6, x6);
      // bitonic lower-4 of 8
      mn(a0, x0, a7, x7); mn(a1, x1, a6, x6); mn(a2, x2, a5, x5); mn(a3, x3, a4, x4);
      ce(a0, x0, a2, x2); ce(a1, x1, a3, x3); ce(a0, x0, a1, x1); ce(a2, x2, a3, x3);
      float c4[4] = {a0, a1, a2, a3};
      int d4[4] = {x0, x1, x2, x3};
      // butterfly across the 16 code-group lanes
      #pragma unroll
      for (int mm_ = 1; mm_ < 16; mm_ <<= 1) {
        float o[4]; int p[4];
        #pragma unroll
        for (int q = 0; q < 4; ++q) {
          o[q] = __shfl_xor(c4[q], mm_, 64);
          p[q] = __shfl_xor(d4[q], mm_, 64);
        }
        merge4(c4, d4, o, p);
      }
      merge4(&mrun[i][0], &jrun[i][0], c4, d4);
    }
  }

  if (tc == 0) {
    #pragma unroll
    for (int i = 0; i < 8; ++i) {
      const int row = row0 + tr * 8 + i;
      candIdx[row * KSPLIT + ks] = make_int4(jrun[i][0], jrun[i][1], jrun[i][2], jrun[i][3]);
    }
  }
}

// ---------------- stage B: literal np-f32 re-score (sequential fmaf chain) + lexmin ----------------
__global__ __launch_bounds__(256) void vq_stageB(const float* __restrict__ z,
                                                 const float* __restrict__ emb,
                                                 const float* __restrict__ zz,
                                                 const float* __restrict__ ee,
                                                 const int4* __restrict__ candIdx,
                                                 float* __restrict__ outq,
                                                 float* __restrict__ outi,
                                                 float* __restrict__ lossAcc) {
#pragma clang fp contract(off)
  __shared__ float lred[8];
  const int tid = threadIdx.x;
  const int grp = tid >> 5;              // 8 rows per block
  const int slot = tid & 31;             // 32 candidates per row
  const int row = blockIdx.x * 8 + grp;

  const int4 c4 = candIdx[row * KSPLIT + (slot >> 2)];
  const int sel = slot & 3;
  const int ci = sel == 0 ? c4.x : sel == 1 ? c4.y : sel == 2 ? c4.z : c4.w;

  // mm via BLAS-order sequential f32 FMA chain over k = 0..255
  const float* zr = z + row * DIM;
  const float* er = emb + ci * DIM;
  float acc = 0.0f;
  #pragma unroll 4
  for (int k = 0; k < DIM; k += 4) {
    const float4 a = *reinterpret_cast<const float4*>(zr + k);
    const float4 b = *reinterpret_cast<const float4*>(er + k);
    acc = fmaf(a.x, b.x, acc);
    acc = fmaf(a.y, b.y, acc);
    acc = fmaf(a.z, b.z, acc);
    acc = fmaf(a.w, b.w, acc);
  }
  // literal np sequence: d = fl(fl(zz + ee) - fl(2*mm))
  const float t = zz[row] + ee[ci];
  const float m2 = 2.0f * acc;
  const float s = t - m2;                // s > 0 always (zz ~ 256)

  unsigned long long pk =
      (((unsigned long long)__float_as_uint(s)) << 32) | (unsigned int)ci;
  #pragma unroll
  for (int mm_ = 1; mm_ < 32; mm_ <<= 1) {
    const unsigned long long o = __shfl_xor(pk, mm_, 64);
    pk = (o < pk) ? o : pk;
  }
  const int bi = (int)(pk & 0xffffffffu);

  // outputs: z_q_st = z + (z_q - z); loss partials
  const float4* eb = reinterpret_cast<const float4*>(emb + bi * DIM);
  const float4* zb = reinterpret_cast<const float4*>(zr);
  float l = 0.0f;
  #pragma unroll
  for (int q = 0; q < 2; ++q) {
    const float4 e4 = eb[slot * 2 + q];
    const float4 z4 = zb[slot * 2 + q];
    float4 o4;
    const float dx = e4.x - z4.x, dy = e4.y - z4.y, dz = e4.z - z4.z, dw = e4.w - z4.w;
    o4.x = z4.x + dx; o4.y = z4.y + dy; o4.z = z4.z + dz; o4.w = z4.w + dw;
    *reinterpret_cast<float4*>(outq + row * DIM + slot * 8 + q * 4) = o4;
    l += dx * dx; l += dy * dy; l += dz * dz; l += dw * dw;
  }
  if (slot == 0) outi[row] = (float)bi;

  #pragma unroll
  for (int mm_ = 1; mm_ < 32; mm_ <<= 1) l += __shfl_xor(l, mm_, 64);
  if (slot == 0) lred[grp] = l;
  __syncthreads();
  if (tid == 0) {
    float tt = 0.f;
    #pragma unroll
    for (int g = 0; g < 8; ++g) tt += lred[g];
    atomicAdd(lossAcc, tt);
  }
}

__global__ void vq_fin(const float* __restrict__ lossAcc, float* __restrict__ outLoss) {
  *outLoss = 1.25f * (*lossAcc) * (1.0f / 4194304.0f);
}

extern "C" void kernel_launch(void* const* d_in, const int* in_sizes, int n_in,
                              void* d_out, int out_size, void* d_ws, size_t ws_size,
                              hipStream_t stream) {
  const float* z = (const float*)d_in[0];
  const float* emb = (const float*)d_in[1];
  float* out = (float*)d_out;
  float* wsf = (float*)d_ws;
  int4* candIdx = (int4*)(wsf + WS_CIDX);
  float* zz = wsf + WS_ZZ;
  float* ee = wsf + WS_EE;
  float* lossAcc = wsf + WS_LOSS;

  vq_prep_zz<<<NROWS / 256, 256, 0, stream>>>(z, zz, lossAcc);
  vq_prep_ee<<<KCODES / 256, 256, 0, stream>>>(emb, ee);
  vq_stageA<<<dim3(KSPLIT, NROWS / BM), 256, 0, stream>>>(z, emb, candIdx);
  vq_stageB<<<NROWS / 8, 256, 0, stream>>>(z, emb, zz, ee, candIdx,
                                           out, out + NROWS * DIM, lossAcc);
  vq_fin<<<1, 1, 0, stream>>>(lossAcc, out + NROWS * DIM + NROWS);
}

// Round 4
// 353.140 us; speedup vs baseline: 3.1421x; 3.1421x over previous
//
#include <hip/hip_runtime.h>
#include <math.h>
#include <float.h>

#define NROWS 16384
#define KCODES 8192
#define DIM 256

// ws layout (4B units)
#define WS_CIDX 0                        // 16384*8 int4 (2 MB)
#define WS_ZZ   (NROWS * 8 * 4)
#define WS_EE   (WS_ZZ + NROWS)
#define WS_LOSS (WS_EE + KCODES)

typedef __attribute__((ext_vector_type(8))) short bf16x8;
typedef __attribute__((ext_vector_type(4))) float f32x4;

__device__ __forceinline__ unsigned cvt2(float lo, float hi) {
  unsigned r;
  asm("v_cvt_pk_bf16_f32 %0, %1, %2" : "=v"(r) : "v"(lo), "v"(hi));
  return r;
}
__device__ __forceinline__ unsigned umn(unsigned a, unsigned b) { return a < b ? a : b; }
__device__ __forceinline__ unsigned umx(unsigned a, unsigned b) { return a > b ? a : b; }
__device__ __forceinline__ void ce32(unsigned& a, unsigned& b) {
  unsigned lo = umn(a, b); b = umx(a, b); a = lo;
}
// merge two ascending 4-lists -> ascending smallest-4
__device__ __forceinline__ void mrg4(unsigned m[4], const unsigned o[4]) {
  m[0] = umn(m[0], o[3]); m[1] = umn(m[1], o[2]);
  m[2] = umn(m[2], o[1]); m[3] = umn(m[3], o[0]);
  ce32(m[0], m[2]); ce32(m[1], m[3]); ce32(m[0], m[1]); ce32(m[2], m[3]);
}
__device__ __forceinline__ void sort4(unsigned& a, unsigned& b, unsigned& c, unsigned& d) {
  ce32(a, b); ce32(c, d); ce32(a, c); ce32(b, d); ce32(b, c);
}

// ---- exact numpy scalar-pairwise sum of squares over 256 contiguous f32 ----
__device__ __forceinline__ float np_sumsq256(const float* __restrict__ p) {
#pragma clang fp contract(off)
  float s0 = 0.f, s1 = 0.f;
  for (int h = 0; h < 2; ++h) {
    const float* x = p + h * 128;
    float r0, r1, r2, r3, r4, r5, r6, r7;
    {
      float4 a = *reinterpret_cast<const float4*>(x);
      float4 b = *reinterpret_cast<const float4*>(x + 4);
      r0 = a.x * a.x; r1 = a.y * a.y; r2 = a.z * a.z; r3 = a.w * a.w;
      r4 = b.x * b.x; r5 = b.y * b.y; r6 = b.z * b.z; r7 = b.w * b.w;
    }
    for (int g = 1; g < 16; ++g) {
      float4 a = *reinterpret_cast<const float4*>(x + g * 8);
      float4 b = *reinterpret_cast<const float4*>(x + g * 8 + 4);
      float p0 = a.x * a.x, p1 = a.y * a.y, p2 = a.z * a.z, p3 = a.w * a.w;
      float p4 = b.x * b.x, p5 = b.y * b.y, p6 = b.z * b.z, p7 = b.w * b.w;
      r0 += p0; r1 += p1; r2 += p2; r3 += p3;
      r4 += p4; r5 += p5; r6 += p6; r7 += p7;
    }
    float t = ((r0 + r1) + (r2 + r3)) + ((r4 + r5) + (r6 + r7));
    if (h == 0) s0 = t; else s1 = t;
  }
  return s0 + s1;
}

__global__ __launch_bounds__(256) void vq_prep_zz(const float* __restrict__ z,
                                                  float* __restrict__ zz,
                                                  float* __restrict__ lossAcc) {
  const int row = blockIdx.x * 256 + threadIdx.x;
  if (row == 0) *lossAcc = 0.0f;
  zz[row] = np_sumsq256(z + row * DIM);
}

__global__ __launch_bounds__(256) void vq_prep_ee(const float* __restrict__ emb,
                                                  float* __restrict__ ee) {
  const int c = blockIdx.x * 256 + threadIdx.x;
  ee[c] = np_sumsq256(emb + c * DIM);
}

// ---------------- stage A: bf16 MFMA ranking + packed-key top-4 per 1024-code range ----------------
// grid: (NROWS/128, 8). Block: 256 thr = 4 waves (wr = wave>>1 row-half, wc = wave&1 code-half).
// Wave tile: 64 rows x 128 codes. cc-loop: 4 x 256-code subtiles. K-chunks: 4 x 64.
__global__ __launch_bounds__(256, 2) void vq_stageA(const float* __restrict__ z,
                                                    const float* __restrict__ emb,
                                                    int4* __restrict__ candIdx) {
  __shared__ short es[256 * 64];                 // [code][k] swizzled, 32 KB
  __shared__ short zs[128 * 64];                 // [row][k] swizzled, 16 KB
  __shared__ unsigned long long mrg[128][2][4];  // cross-wave merge buffer, 8 KB

  const int tid = threadIdx.x;
  const int wave = tid >> 6, lane = tid & 63;
  const int wr = wave >> 1, wc = wave & 1;
  const int g = lane >> 4, r16 = lane & 15;
  const int rowBase = blockIdx.x * 128;
  const int crange = blockIdx.y;                 // 0..7 -> codes [crange*1024, +1024)
  const int swz = (r16 & 7) << 4;

  unsigned run[4][4];                            // [bj][q] ascending keys
  #pragma unroll
  for (int bj = 0; bj < 4; ++bj)
    #pragma unroll
    for (int q = 0; q < 4; ++q) run[bj][q] = 0xFFFFFFFFu;

  for (int cc = 0; cc < 4; ++cc) {
    const int cbase = crange * 1024 + cc * 256;
    f32x4 acc[8][4];
    #pragma unroll
    for (int ai = 0; ai < 8; ++ai)
      #pragma unroll
      for (int bj = 0; bj < 4; ++bj) acc[ai][bj] = (f32x4){0.f, 0.f, 0.f, 0.f};

    for (int kc = 0; kc < 4; ++kc) {
      const int d0 = kc * 64;
      __syncthreads();   // protect LDS from previous iteration's readers
      // stage e: 256 codes x 64 f32 -> bf16 (8 iters x (2 float4 -> 1 b128))
      #pragma unroll
      for (int i = 0; i < 8; ++i) {
        const int f8 = i * 256 + tid;
        const int row = f8 >> 3, c8 = f8 & 7;
        const float4* p = reinterpret_cast<const float4*>(emb + (cbase + row) * DIM + d0 + c8 * 8);
        const float4 a = p[0], b = p[1];
        const unsigned u0 = cvt2(a.x, a.y), u1 = cvt2(a.z, a.w);
        const unsigned u2 = cvt2(b.x, b.y), u3 = cvt2(b.z, b.w);
        const int byte = (row * 128 + c8 * 16) ^ ((row & 7) << 4);
        *reinterpret_cast<uint4*>(reinterpret_cast<char*>(es) + byte) = make_uint4(u0, u1, u2, u3);
      }
      // stage z: 128 rows x 64 f32 (4 iters)
      #pragma unroll
      for (int i = 0; i < 4; ++i) {
        const int f8 = i * 256 + tid;
        const int row = f8 >> 3, c8 = f8 & 7;
        const float4* p = reinterpret_cast<const float4*>(z + (rowBase + row) * DIM + d0 + c8 * 8);
        const float4 a = p[0], b = p[1];
        const unsigned u0 = cvt2(a.x, a.y), u1 = cvt2(a.z, a.w);
        const unsigned u2 = cvt2(b.x, b.y), u3 = cvt2(b.z, b.w);
        const int byte = (row * 128 + c8 * 16) ^ ((row & 7) << 4);
        *reinterpret_cast<uint4*>(reinterpret_cast<char*>(zs) + byte) = make_uint4(u0, u1, u2, u3);
      }
      __syncthreads();

      #pragma unroll
      for (int ks2 = 0; ks2 < 2; ++ks2) {
        const int kb = ks2 * 64 + g * 16;        // byte offset within a 128B k-row
        bf16x8 A[8], B[4];
        #pragma unroll
        for (int ai = 0; ai < 8; ++ai) {
          const int cl = wc * 128 + ai * 16 + r16;
          A[ai] = *reinterpret_cast<const bf16x8*>(
              reinterpret_cast<const char*>(es) + ((cl * 128 + kb) ^ swz));
        }
        #pragma unroll
        for (int bj = 0; bj < 4; ++bj) {
          const int rl = wr * 64 + bj * 16 + r16;
          B[bj] = *reinterpret_cast<const bf16x8*>(
              reinterpret_cast<const char*>(zs) + ((rl * 128 + kb) ^ swz));
        }
        #pragma unroll
        for (int ai = 0; ai < 8; ++ai)
          #pragma unroll
          for (int bj = 0; bj < 4; ++bj)
            acc[ai][bj] = __builtin_amdgcn_mfma_f32_16x16x32_bf16(A[ai], B[bj], acc[ai][bj], 0, 0, 0);
      }
    }

    // selection: packed keys, top-4 per (row, this cc-subtile) merged into running top-4
    #pragma unroll
    for (int bj = 0; bj < 4; ++bj) {
      unsigned q4[8][4];
      #pragma unroll
      for (int ai = 0; ai < 8; ++ai) {
        const unsigned base9 = (cc << 7) | (ai << 4) | (g << 2);
        unsigned k0 = (__float_as_uint(1.5f - acc[ai][bj][0]) << 9) | base9;
        unsigned k1 = (__float_as_uint(1.5f - acc[ai][bj][1]) << 9) | (base9 + 1);
        unsigned k2 = (__float_as_uint(1.5f - acc[ai][bj][2]) << 9) | (base9 + 2);
        unsigned k3 = (__float_as_uint(1.5f - acc[ai][bj][3]) << 9) | (base9 + 3);
        sort4(k0, k1, k2, k3);
        q4[ai][0] = k0; q4[ai][1] = k1; q4[ai][2] = k2; q4[ai][3] = k3;
      }
      mrg4(q4[0], q4[1]); mrg4(q4[2], q4[3]); mrg4(q4[4], q4[5]); mrg4(q4[6], q4[7]);
      mrg4(q4[0], q4[2]); mrg4(q4[4], q4[6]);
      mrg4(q4[0], q4[4]);
      mrg4(run[bj], q4[0]);
    }
  }

  // butterfly across the 4 k-lane groups (xor 16, 32): merge per-lane column-sets
  #pragma unroll
  for (int bj = 0; bj < 4; ++bj) {
    #pragma unroll
    for (int m = 16; m < 64; m <<= 1) {
      unsigned o[4];
      #pragma unroll
      for (int q = 0; q < 4; ++q) o[q] = __shfl_xor(run[bj][q], m, 64);
      mrg4(run[bj], o);
    }
  }
  // write per-wave top-4 (u64 keys with global code-in-range) to LDS
  if (lane < 16) {
    #pragma unroll
    for (int bj = 0; bj < 4; ++bj) {
      const int rl = wr * 64 + bj * 16 + r16;
      #pragma unroll
      for (int q = 0; q < 4; ++q) {
        const unsigned k = run[bj][q];
        const unsigned cid = k & 511u;
        const unsigned cir = ((cid >> 7) << 8) | (wc << 7) | (cid & 127u);
        mrg[rl][wc][q] = (((unsigned long long)(k >> 9)) << 10) | cir;
      }
    }
  }
  __syncthreads();
  // final cross-wave (wc) merge + candIdx write
  if (tid < 128) {
    unsigned long long a0 = mrg[tid][0][0], a1 = mrg[tid][0][1], a2 = mrg[tid][0][2], a3 = mrg[tid][0][3];
    unsigned long long b0 = mrg[tid][1][0], b1 = mrg[tid][1][1], b2 = mrg[tid][1][2], b3 = mrg[tid][1][3];
    a0 = a0 < b3 ? a0 : b3; a1 = a1 < b2 ? a1 : b2;
    a2 = a2 < b1 ? a2 : b1; a3 = a3 < b0 ? a3 : b0;
    unsigned long long t;
    if (a2 < a0) { t = a0; a0 = a2; a2 = t; }
    if (a3 < a1) { t = a1; a1 = a3; a3 = t; }
    if (a1 < a0) { t = a0; a0 = a1; a1 = t; }
    if (a3 < a2) { t = a2; a2 = a3; a3 = t; }
    const int base = crange * 1024;
    candIdx[(rowBase + tid) * 8 + crange] =
        make_int4(base + (int)(a0 & 1023u), base + (int)(a1 & 1023u),
                  base + (int)(a2 & 1023u), base + (int)(a3 & 1023u));
  }
}

// ---------------- stage B: literal np-f32 re-score (sequential fmaf chain) + lexmin ----------------
__global__ __launch_bounds__(256) void vq_stageB(const float* __restrict__ z,
                                                 const float* __restrict__ emb,
                                                 const float* __restrict__ zz,
                                                 const float* __restrict__ ee,
                                                 const int4* __restrict__ candIdx,
                                                 float* __restrict__ outq,
                                                 float* __restrict__ outi,
                                                 float* __restrict__ lossAcc) {
#pragma clang fp contract(off)
  __shared__ float lred[8];
  const int tid = threadIdx.x;
  const int grp = tid >> 5;              // 8 rows per block
  const int slot = tid & 31;             // 32 candidates per row
  const int row = blockIdx.x * 8 + grp;

  const int4 c4 = candIdx[row * 8 + (slot >> 2)];
  const int sel = slot & 3;
  const int ci = sel == 0 ? c4.x : sel == 1 ? c4.y : sel == 2 ? c4.z : c4.w;

  // mm via BLAS-order sequential f32 FMA chain over k = 0..255
  const float* zr = z + row * DIM;
  const float* er = emb + ci * DIM;
  float acc = 0.0f;
  #pragma unroll 4
  for (int k = 0; k < DIM; k += 4) {
    const float4 a = *reinterpret_cast<const float4*>(zr + k);
    const float4 b = *reinterpret_cast<const float4*>(er + k);
    acc = fmaf(a.x, b.x, acc);
    acc = fmaf(a.y, b.y, acc);
    acc = fmaf(a.z, b.z, acc);
    acc = fmaf(a.w, b.w, acc);
  }
  // literal np sequence: d = fl(fl(zz + ee) - fl(2*mm))
  const float t = zz[row] + ee[ci];
  const float m2 = 2.0f * acc;
  const float s = t - m2;                // s > 0 always (zz ~ 256)

  unsigned long long pk =
      (((unsigned long long)__float_as_uint(s)) << 32) | (unsigned int)ci;
  #pragma unroll
  for (int mm_ = 1; mm_ < 32; mm_ <<= 1) {
    const unsigned long long o = __shfl_xor(pk, mm_, 64);
    pk = (o < pk) ? o : pk;
  }
  const int bi = (int)(pk & 0xffffffffu);

  // outputs: z_q_st = z + (z_q - z); loss partials
  const float4* eb = reinterpret_cast<const float4*>(emb + bi * DIM);
  const float4* zb = reinterpret_cast<const float4*>(zr);
  float l = 0.0f;
  #pragma unroll
  for (int q = 0; q < 2; ++q) {
    const float4 e4 = eb[slot * 2 + q];
    const float4 z4 = zb[slot * 2 + q];
    float4 o4;
    const float dx = e4.x - z4.x, dy = e4.y - z4.y, dz = e4.z - z4.z, dw = e4.w - z4.w;
    o4.x = z4.x + dx; o4.y = z4.y + dy; o4.z = z4.z + dz; o4.w = z4.w + dw;
    *reinterpret_cast<float4*>(outq + row * DIM + slot * 8 + q * 4) = o4;
    l += dx * dx; l += dy * dy; l += dz * dz; l += dw * dw;
  }
  if (slot == 0) outi[row] = (float)bi;

  #pragma unroll
  for (int mm_ = 1; mm_ < 32; mm_ <<= 1) l += __shfl_xor(l, mm_, 64);
  if (slot == 0) lred[grp] = l;
  __syncthreads();
  if (tid == 0) {
    float tt = 0.f;
    #pragma unroll
    for (int g = 0; g < 8; ++g) tt += lred[g];
    atomicAdd(lossAcc, tt);
  }
}

__global__ void vq_fin(const float* __restrict__ lossAcc, float* __restrict__ outLoss) {
  *outLoss = 1.25f * (*lossAcc) * (1.0f / 4194304.0f);
}

extern "C" void kernel_launch(void* const* d_in, const int* in_sizes, int n_in,
                              void* d_out, int out_size, void* d_ws, size_t ws_size,
                              hipStream_t stream) {
  const float* z = (const float*)d_in[0];
  const float* emb = (const float*)d_in[1];
  float* out = (float*)d_out;
  float* wsf = (float*)d_ws;
  int4* candIdx = (int4*)(wsf + WS_CIDX);
  float* zz = wsf + WS_ZZ;
  float* ee = wsf + WS_EE;
  float* lossAcc = wsf + WS_LOSS;

  vq_prep_zz<<<NROWS / 256, 256, 0, stream>>>(z, zz, lossAcc);
  vq_prep_ee<<<KCODES / 256, 256, 0, stream>>>(emb, ee);
  vq_stageA<<<dim3(NROWS / 128, 8), 256, 0, stream>>>(z, emb, candIdx);
  vq_stageB<<<NROWS / 8, 256, 0, stream>>>(z, emb, zz, ee, candIdx,
                                           out, out + NROWS * DIM, lossAcc);
  vq_fin<<<1, 1, 0, stream>>>(lossAcc, out + NROWS * DIM + NROWS);
}